// Round 1
// baseline (477.453 us; speedup 1.0000x reference)
//
#include <hip/hip_runtime.h>
#include <hip/hip_bf16.h>
#include <math.h>

typedef unsigned short u16;
typedef __attribute__((ext_vector_type(8))) __bf16 bf16x8;
typedef __attribute__((ext_vector_type(4))) float floatx4;

#define SEQ   4096
#define BATCH 8
#define ROWS  32768   // BATCH*SEQ
#define C     512
#define NH    16
#define HD    32
#define LDST  56      // LDS row stride in shorts: 112B, 112/16=7 coprime w/ 8 -> 2-way only

__device__ inline u16 f2bf(float f) {
    union { float f; unsigned u; } v; v.f = f;
    unsigned r = (v.u + 0x7FFFu + ((v.u >> 16) & 1u)) >> 16;
    return (u16)r;
}
__device__ inline float bf2f(u16 h) {
    union { unsigned u; float f; } v; v.u = ((unsigned)h) << 16;
    return v.f;
}

// ---------------- weight prep: fp32 (k,n) -> bf16 transposed (n,k) ----------------
__global__ __launch_bounds__(256) void prep_weights(
    const float* __restrict__ Wq, const float* __restrict__ Wk,
    const float* __restrict__ Wv, const float* __restrict__ Wm,
    const float* __restrict__ W1, const float* __restrict__ W2,
    u16* __restrict__ Wqkvt, u16* __restrict__ Wmt,
    u16* __restrict__ W1t, u16* __restrict__ W2t)
{
    int t = blockIdx.x * 256 + threadIdx.x;   // 0 .. 6*512*512-1
    int mat = t >> 18;
    int idx = t & 0x3FFFF;                    // n*512 + k
    int n = idx >> 9, k = idx & 511;
    const float* src; u16* dst;
    switch (mat) {
        case 0: src = Wq; dst = Wqkvt;              break;
        case 1: src = Wk; dst = Wqkvt + 512*512;    break;
        case 2: src = Wv; dst = Wqkvt + 2*512*512;  break;
        case 3: src = Wm; dst = Wmt;                break;
        case 4: src = W1; dst = W1t;                break;
        default: src = W2; dst = W2t;               break;
    }
    dst[idx] = f2bf(src[k * 512 + n]);
}

// ---------------- layernorm: fp32 in -> bf16 out, one wave per row ----------------
__global__ __launch_bounds__(256) void ln_kernel(
    const float* __restrict__ in, const float* __restrict__ g,
    const float* __restrict__ b, u16* __restrict__ out)
{
    int row  = blockIdx.x * 4 + (threadIdx.x >> 6);
    int lane = threadIdx.x & 63;
    const float* p = in + (size_t)row * C + lane * 8;
    float4 v0 = *(const float4*)p;
    float4 v1 = *(const float4*)(p + 4);
    float s  = v0.x + v0.y + v0.z + v0.w + v1.x + v1.y + v1.z + v1.w;
    float s2 = v0.x*v0.x + v0.y*v0.y + v0.z*v0.z + v0.w*v0.w
             + v1.x*v1.x + v1.y*v1.y + v1.z*v1.z + v1.w*v1.w;
    #pragma unroll
    for (int off = 1; off < 64; off <<= 1) {
        s  += __shfl_xor(s, off);
        s2 += __shfl_xor(s2, off);
    }
    float mean = s * (1.f / C);
    float var  = s2 * (1.f / C) - mean * mean;
    float inv  = rsqrtf(var + 1e-6f);
    int c = lane * 8;
    float4 g0 = *(const float4*)(g + c), g1 = *(const float4*)(g + c + 4);
    float4 b0 = *(const float4*)(b + c), b1 = *(const float4*)(b + c + 4);
    union { uint4 v; u16 u[8]; } o;
    o.u[0] = f2bf((v0.x - mean) * inv * g0.x + b0.x);
    o.u[1] = f2bf((v0.y - mean) * inv * g0.y + b0.y);
    o.u[2] = f2bf((v0.z - mean) * inv * g0.z + b0.z);
    o.u[3] = f2bf((v0.w - mean) * inv * g0.w + b0.w);
    o.u[4] = f2bf((v1.x - mean) * inv * g1.x + b1.x);
    o.u[5] = f2bf((v1.y - mean) * inv * g1.y + b1.y);
    o.u[6] = f2bf((v1.z - mean) * inv * g1.z + b1.z);
    o.u[7] = f2bf((v1.w - mean) * inv * g1.w + b1.w);
    *(uint4*)(out + (size_t)row * C + c) = o.v;
}

// ---------------- bf16 MFMA GEMM, 128x128 tile, BK=32 ----------------
// A: M x K row-major bf16.  Bt: N x K row-major bf16 (i.e. B transposed).
// EPI 0: qkv epilogue (elu+1 on cols<1024, /SEQ on v part) -> bf16
// EPI 1: out_f32 = resid + acc
// EPI 2: bf16 = gelu(acc + bias[col])
// EPI 3: out_f32 = out_f32(in place) + acc + bias[col]
template <int EPI>
__global__ __launch_bounds__(256, 2) void gemm_tile(
    const u16* __restrict__ A, const u16* __restrict__ Bt,
    int M, int N, int K, int ldc,
    u16* __restrict__ outb, float* __restrict__ outf,
    const float* __restrict__ bias, const float* __restrict__ resid)
{
    __shared__ u16 lsA[128 * LDST];
    __shared__ u16 lsB[128 * LDST];
    const int t = threadIdx.x;
    const int w = t >> 6, l = t & 63, lr = l & 15, quad = l >> 4;
    const int m0 = blockIdx.y * 128, n0 = blockIdx.x * 128;
    const int RW = (w >> 1) * 64, CW = (w & 1) * 64;

    floatx4 acc[4][4];
    #pragma unroll
    for (int i = 0; i < 4; i++)
        #pragma unroll
        for (int j = 0; j < 4; j++) { floatx4 z = {0.f, 0.f, 0.f, 0.f}; acc[i][j] = z; }

    const int arow = t >> 2, acol = (t & 3) * 8;
    const u16* Ag = A  + (size_t)(m0 + arow) * K + acol;
    const u16* Bg = Bt + (size_t)(n0 + arow) * K + acol;
    const int lo  = arow * LDST + acol;
    const int lo2 = lo + 64 * LDST;

    for (int kk = 0; kk < K; kk += 32) {
        uint4 a0 = *(const uint4*)(Ag + kk);
        uint4 a1 = *(const uint4*)(Ag + (size_t)64 * K + kk);
        uint4 b0 = *(const uint4*)(Bg + kk);
        uint4 b1 = *(const uint4*)(Bg + (size_t)64 * K + kk);
        __syncthreads();
        *(uint4*)(lsA + lo)  = a0;
        *(uint4*)(lsA + lo2) = a1;
        *(uint4*)(lsB + lo)  = b0;
        *(uint4*)(lsB + lo2) = b1;
        __syncthreads();
        bf16x8 af[4], bf[4];
        #pragma unroll
        for (int i = 0; i < 4; i++) {
            af[i] = *(const bf16x8*)(lsA + (RW + i * 16 + lr) * LDST + quad * 8);
            bf[i] = *(const bf16x8*)(lsB + (CW + i * 16 + lr) * LDST + quad * 8);
        }
        #pragma unroll
        for (int i = 0; i < 4; i++)
            #pragma unroll
            for (int j = 0; j < 4; j++)
                acc[i][j] = __builtin_amdgcn_mfma_f32_16x16x32_bf16(af[i], bf[j], acc[i][j], 0, 0, 0);
    }

    #pragma unroll
    for (int i = 0; i < 4; i++) {
        #pragma unroll
        for (int j = 0; j < 4; j++) {
            #pragma unroll
            for (int r = 0; r < 4; r++) {
                int row = m0 + RW + i * 16 + quad * 4 + r;
                int col = n0 + CW + j * 16 + lr;
                float v = acc[i][j][r];
                size_t idx = (size_t)row * ldc + col;
                if constexpr (EPI == 0) {
                    if (col < 1024) v = v > 0.f ? v + 1.f : __expf(v);
                    else            v *= (1.0f / SEQ);
                    outb[idx] = f2bf(v);
                } else if constexpr (EPI == 1) {
                    outf[idx] = resid[idx] + v;
                } else if constexpr (EPI == 2) {
                    v += bias[col];
                    v = 0.5f * v * (1.f + erff(v * 0.70710678118f));
                    outb[idx] = f2bf(v);
                } else {
                    outf[idx] = outf[idx] + v + bias[col];
                }
            }
        }
    }
}

// ---------------- zero fill ----------------
__global__ __launch_bounds__(256) void zero_kernel(float* p, int n) {
    int i = blockIdx.x * 256 + threadIdx.x;
    if (i < n) p[i] = 0.f;
}

// ---------------- KV = sum_s K outer v ; Ksum = sum_s K. split over N chunks ----------------
__global__ __launch_bounds__(256) void kv_reduce(
    const u16* __restrict__ qkv, float* __restrict__ KV, float* __restrict__ Ksum)
{
    int bh = blockIdx.x;            // 0..127
    int b = bh >> 4, h = bh & 15;
    int chunk = blockIdx.y;         // 0..7
    int t = threadIdx.x;
    __shared__ float Ks[32 * 32];
    __shared__ float Vs[32 * 32];
    int d  = t & 31;
    int vd = (t >> 5) << 2;
    float a0 = 0.f, a1 = 0.f, a2 = 0.f, a3 = 0.f, ks = 0.f;
    int s0 = chunk * 512;
    const size_t base = (size_t)b * SEQ * 1536 + 512 + h * HD;
    for (int so = 0; so < 512; so += 32) {
        __syncthreads();
        #pragma unroll
        for (int i = 0; i < 4; i++) {
            int e = i * 256 + t;
            int sl = e >> 5, dd = e & 31;
            size_t gp = base + (size_t)(s0 + so + sl) * 1536 + dd;
            Ks[e] = bf2f(qkv[gp]);
            Vs[e] = bf2f(qkv[gp + 512]);
        }
        __syncthreads();
        #pragma unroll
        for (int s = 0; s < 32; s++) {
            float kvv = Ks[s * 32 + d];
            float4 vv = *(const float4*)(Vs + s * 32 + vd);
            a0 += kvv * vv.x; a1 += kvv * vv.y; a2 += kvv * vv.z; a3 += kvv * vv.w;
            ks += kvv;
        }
    }
    float* kvp = KV + (size_t)bh * 1024 + d * 32 + vd;
    atomicAdd(kvp + 0, a0);
    atomicAdd(kvp + 1, a1);
    atomicAdd(kvp + 2, a2);
    atomicAdd(kvp + 3, a3);
    if (t < 32) atomicAdd(Ksum + bh * 32 + t, ks);
}

// ---------------- msg = (Q . KV) * SEQ / (Q . Ksum + eps) ----------------
__global__ __launch_bounds__(256) void msg_kernel(
    const u16* __restrict__ qkv, const float* __restrict__ KV,
    const float* __restrict__ Ksum, u16* __restrict__ msg)
{
    int blk = blockIdx.x;           // 0..511
    int b = blk >> 6;
    int r0 = (blk & 63) * 64;
    int t = threadIdx.x;
    int h = t >> 4;
    int vd = (t & 15) * 2;
    __shared__ float KVs[16 * 1024];
    __shared__ float Kss[16 * 32];
    for (int i = t; i < 16 * 1024; i += 256) KVs[i] = KV[(size_t)b * 16 * 1024 + i];
    for (int i = t; i < 512; i += 256) Kss[i] = Ksum[b * 512 + i];
    __syncthreads();
    const float* kvh = KVs + h * 1024;
    const float* ksh = Kss + h * 32;
    for (int rr = 0; rr < 64; rr++) {
        size_t row = (size_t)b * SEQ + r0 + rr;
        const u16* Qp = qkv + row * 1536 + h * HD;
        float q[32];
        #pragma unroll
        for (int i0 = 0; i0 < 32; i0 += 8) {
            union { uint4 v; u16 u[8]; } uu;
            uu.v = *(const uint4*)(Qp + i0);
            #pragma unroll
            for (int j = 0; j < 8; j++) q[i0 + j] = bf2f(uu.u[j]);
        }
        float zdot = 0.f, msum0 = 0.f, msum1 = 0.f;
        #pragma unroll
        for (int d = 0; d < 32; d++) {
            float qd = q[d];
            zdot  += qd * ksh[d];
            msum0 += qd * kvh[d * 32 + vd];
            msum1 += qd * kvh[d * 32 + vd + 1];
        }
        float z = (float)SEQ / (zdot + 1e-6f);
        unsigned pack = (unsigned)f2bf(msum0 * z) | ((unsigned)f2bf(msum1 * z) << 16);
        *(unsigned*)(msg + row * C + h * HD + vd) = pack;
    }
}

extern "C" void kernel_launch(void* const* d_in, const int* in_sizes, int n_in,
                              void* d_out, int out_size, void* d_ws, size_t ws_size,
                              hipStream_t stream) {
    const float* x     = (const float*)d_in[0];
    const float* Wq    = (const float*)d_in[1];
    const float* Wk    = (const float*)d_in[2];
    const float* Wv    = (const float*)d_in[3];
    const float* Wm    = (const float*)d_in[4];
    const float* W1    = (const float*)d_in[5];
    const float* b1    = (const float*)d_in[6];
    const float* W2    = (const float*)d_in[7];
    const float* b2    = (const float*)d_in[8];
    const float* g_att = (const float*)d_in[9];
    const float* b_att = (const float*)d_in[10];
    const float* g_ffn = (const float*)d_in[11];
    const float* b_ffn = (const float*)d_in[12];
    float* out = (float*)d_out;

    char* ws = (char*)d_ws;
    u16*   Wqkvt = (u16*)(ws);                    // 1.5 MB
    u16*   Wmt   = (u16*)(ws + 0x180000);         // 0.5 MB
    u16*   W1t   = (u16*)(ws + 0x200000);         // 0.5 MB
    u16*   W2t   = (u16*)(ws + 0x280000);         // 0.5 MB
    float* KV    = (float*)(ws + 0x300000);       // 512 KB
    float* Ksum  = (float*)(ws + 0x380000);       // 16 KB (contiguous after KV)
    u16*   hb    = (u16*)(ws + 0x400000);         // 32 MB (LN1 out; reused as msg)
    u16*   qkv   = (u16*)(ws + 0x2400000);        // 96 MB (reused: h2, f1)
    u16*   h2    = qkv;                           // 32 MB
    u16*   f1    = (u16*)(ws + 0x4400000);        // 32 MB
    // total ws use: 132 MB

    // 1. weights -> bf16 transposed
    prep_weights<<<6 * 512 * 512 / 256, 256, 0, stream>>>(Wq, Wk, Wv, Wm, W1, W2,
                                                          Wqkvt, Wmt, W1t, W2t);
    // 2. LN1
    ln_kernel<<<ROWS / 4, 256, 0, stream>>>(x, g_att, b_att, hb);
    // 3. qkv = h @ [Wq|Wk|Wv] with feature-map epilogue
    gemm_tile<0><<<dim3(12, 256), 256, 0, stream>>>(hb, Wqkvt, ROWS, 1536, 512, 1536,
                                                    qkv, nullptr, nullptr, nullptr);
    // 4. zero KV+Ksum (132k floats), then reduce
    zero_kernel<<<(128 * 1024 + 128 * 32 + 255) / 256, 256, 0, stream>>>(KV, 128 * 1024 + 128 * 32);
    kv_reduce<<<dim3(128, 8), 256, 0, stream>>>(qkv, KV, Ksum);
    // 5. msg
    msg_kernel<<<512, 256, 0, stream>>>(qkv, KV, Ksum, hb);
    // 6. x2 = x + msg @ Wm   (x2 lives in d_out)
    gemm_tile<1><<<dim3(4, 256), 256, 0, stream>>>(hb, Wmt, ROWS, 512, 512, 512,
                                                   nullptr, out, nullptr, x);
    // 7. LN2
    ln_kernel<<<ROWS / 4, 256, 0, stream>>>(out, g_ffn, b_ffn, h2);
    // 8. f1 = gelu(h2 @ W1 + b1)
    gemm_tile<2><<<dim3(4, 256), 256, 0, stream>>>(h2, W1t, ROWS, 512, 512, 512,
                                                   f1, nullptr, b1, nullptr);
    // 9. out = x2 + f1 @ W2 + b2   (in place on d_out)
    gemm_tile<3><<<dim3(4, 256), 256, 0, stream>>>(f1, W2t, ROWS, 512, 512, 512,
                                                   nullptr, out, b2, nullptr);
}

// Round 2
// 471.813 us; speedup vs baseline: 1.0120x; 1.0120x over previous
//
#include <hip/hip_runtime.h>
#include <hip/hip_bf16.h>
#include <math.h>

typedef unsigned short u16;
typedef __attribute__((ext_vector_type(8))) __bf16 bf16x8;
typedef __attribute__((ext_vector_type(4))) float floatx4;

#define SEQ   4096
#define BATCH 8
#define ROWS  32768   // BATCH*SEQ
#define C     512
#define NH    16
#define HD    32

__device__ inline u16 f2bf(float f) {
    union { float f; unsigned u; } v; v.f = f;
    unsigned r = (v.u + 0x7FFFu + ((v.u >> 16) & 1u)) >> 16;
    return (u16)r;
}
__device__ inline float bf2f(u16 h) {
    union { unsigned u; float f; } v; v.u = ((unsigned)h) << 16;
    return v.f;
}

// async global -> LDS, 16B per lane; lds ptr must be wave-uniform (HW adds lane*16)
__device__ inline void g2lds16(const u16* g, u16* l) {
    __builtin_amdgcn_global_load_lds((const __attribute__((address_space(1))) unsigned*)g,
                                     (__attribute__((address_space(3))) unsigned*)l, 16, 0, 0);
}

// ---------------- weight prep: fp32 (k,n) -> bf16 transposed (n,k), 64x64 LDS tiles ----------------
__global__ __launch_bounds__(256) void prep_weights(
    const float* __restrict__ Wq, const float* __restrict__ Wk,
    const float* __restrict__ Wv, const float* __restrict__ Wm,
    const float* __restrict__ W1, const float* __restrict__ W2,
    u16* __restrict__ Wqkvt, u16* __restrict__ Wmt,
    u16* __restrict__ W1t, u16* __restrict__ W2t)
{
    int blk = blockIdx.x;                 // 6 mats * 64 tiles
    int mat = blk >> 6;
    int tile = blk & 63;
    int k0 = (tile >> 3) * 64, n0 = (tile & 7) * 64;
    const float* src; u16* dst;
    switch (mat) {
        case 0: src = Wq; dst = Wqkvt;              break;
        case 1: src = Wk; dst = Wqkvt + 512*512;    break;
        case 2: src = Wv; dst = Wqkvt + 2*512*512;  break;
        case 3: src = Wm; dst = Wmt;                break;
        case 4: src = W1; dst = W1t;                break;
        default: src = W2; dst = W2t;               break;
    }
    __shared__ float ts[64][65];
    int t = threadIdx.x;
    #pragma unroll
    for (int i = 0; i < 16; i++) {
        int e = i * 256 + t;
        int kr = e >> 6, nc = e & 63;
        ts[kr][nc] = src[(size_t)(k0 + kr) * 512 + n0 + nc];   // coalesced 256B rows
    }
    __syncthreads();
    #pragma unroll
    for (int i = 0; i < 2; i++) {
        int e = i * 256 + t;                 // 512 chunks of 8
        int nr = e >> 3, kc0 = (e & 7) * 8;
        union { uint4 v; u16 u[8]; } o;
        #pragma unroll
        for (int q = 0; q < 8; q++) o.u[q] = f2bf(ts[kc0 + q][nr]);
        *(uint4*)(dst + (size_t)(n0 + nr) * 512 + k0 + kc0) = o.v;   // coalesced 16B stores
    }
}

// ---------------- layernorm: fp32 in -> bf16 out, one wave per row ----------------
__global__ __launch_bounds__(256) void ln_kernel(
    const float* __restrict__ in, const float* __restrict__ g,
    const float* __restrict__ b, u16* __restrict__ out)
{
    int row  = blockIdx.x * 4 + (threadIdx.x >> 6);
    int lane = threadIdx.x & 63;
    const float* p = in + (size_t)row * C + lane * 8;
    float4 v0 = *(const float4*)p;
    float4 v1 = *(const float4*)(p + 4);
    float s  = v0.x + v0.y + v0.z + v0.w + v1.x + v1.y + v1.z + v1.w;
    float s2 = v0.x*v0.x + v0.y*v0.y + v0.z*v0.z + v0.w*v0.w
             + v1.x*v1.x + v1.y*v1.y + v1.z*v1.z + v1.w*v1.w;
    #pragma unroll
    for (int off = 1; off < 64; off <<= 1) {
        s  += __shfl_xor(s, off);
        s2 += __shfl_xor(s2, off);
    }
    float mean = s * (1.f / C);
    float var  = s2 * (1.f / C) - mean * mean;
    float inv  = rsqrtf(var + 1e-6f);
    int c = lane * 8;
    float4 g0 = *(const float4*)(g + c), g1 = *(const float4*)(g + c + 4);
    float4 b0 = *(const float4*)(b + c), b1 = *(const float4*)(b + c + 4);
    union { uint4 v; u16 u[8]; } o;
    o.u[0] = f2bf((v0.x - mean) * inv * g0.x + b0.x);
    o.u[1] = f2bf((v0.y - mean) * inv * g0.y + b0.y);
    o.u[2] = f2bf((v0.z - mean) * inv * g0.z + b0.z);
    o.u[3] = f2bf((v0.w - mean) * inv * g0.w + b0.w);
    o.u[4] = f2bf((v1.x - mean) * inv * g1.x + b1.x);
    o.u[5] = f2bf((v1.y - mean) * inv * g1.y + b1.y);
    o.u[6] = f2bf((v1.z - mean) * inv * g1.z + b1.z);
    o.u[7] = f2bf((v1.w - mean) * inv * g1.w + b1.w);
    *(uint4*)(out + (size_t)row * C + c) = o.v;
}

// ---------------- bf16 MFMA GEMM, 128x128 tile, BK=32, global_load_lds staging ----------------
// A: M x K row-major bf16.  Bt: N x K row-major bf16.
// LDS tile: 128 rows x 32 shorts contiguous (no padding - required by global_load_lds).
// EPI 0: qkv epilogue (elu+1 on cols<1024, /SEQ on v part) -> bf16
// EPI 1: out_f32 = resid + acc
// EPI 2: bf16 = gelu(acc + bias[col])
// EPI 3: out_f32 = out_f32(in place) + acc + bias[col]
template <int EPI>
__global__ __launch_bounds__(256, 2) void gemm_tile(
    const u16* __restrict__ A, const u16* __restrict__ Bt,
    int K, int ldc,
    u16* __restrict__ outb, float* __restrict__ outf,
    const float* __restrict__ bias, const float* __restrict__ resid)
{
    __shared__ u16 lsA[128 * 32];
    __shared__ u16 lsB[128 * 32];
    const int t = threadIdx.x;
    const int w = t >> 6, l = t & 63, lr = l & 15, quad = l >> 4;
    const int m0 = blockIdx.y * 128, n0 = blockIdx.x * 128;
    const int RW = (w >> 1) * 64, CW = (w & 1) * 64;

    floatx4 acc[4][4];
    #pragma unroll
    for (int i = 0; i < 4; i++)
        #pragma unroll
        for (int j = 0; j < 4; j++) { floatx4 z = {0.f, 0.f, 0.f, 0.f}; acc[i][j] = z; }

    // wave w stages chunks 2w, 2w+1 (512 shorts each); lane covers 8 shorts at e = chunk*512 + l*8
    const int e0 = w * 1024 + l * 8;
    const int e1 = e0 + 512;
    const u16* Ag0 = A  + (size_t)(m0 + (e0 >> 5)) * K + (e0 & 31);
    const u16* Ag1 = A  + (size_t)(m0 + (e1 >> 5)) * K + (e1 & 31);
    const u16* Bg0 = Bt + (size_t)(n0 + (e0 >> 5)) * K + (e0 & 31);
    const u16* Bg1 = Bt + (size_t)(n0 + (e1 >> 5)) * K + (e1 & 31);
    u16* lA0 = lsA + w * 1024;          // wave-uniform bases
    u16* lA1 = lsA + w * 1024 + 512;
    u16* lB0 = lsB + w * 1024;
    u16* lB1 = lsB + w * 1024 + 512;

    for (int kk = 0; kk < K; kk += 32) {
        __syncthreads();                 // prior compute done before overwriting LDS
        g2lds16(Ag0 + kk, lA0);
        g2lds16(Ag1 + kk, lA1);
        g2lds16(Bg0 + kk, lB0);
        g2lds16(Bg1 + kk, lB1);
        __syncthreads();                 // vmcnt(0) drain before reading LDS
        bf16x8 af[4], bfr[4];
        #pragma unroll
        for (int i = 0; i < 4; i++) {
            af[i]  = *(const bf16x8*)(lsA + (RW + i * 16 + lr) * 32 + quad * 8);
            bfr[i] = *(const bf16x8*)(lsB + (CW + i * 16 + lr) * 32 + quad * 8);
        }
        #pragma unroll
        for (int i = 0; i < 4; i++)
            #pragma unroll
            for (int j = 0; j < 4; j++)
                acc[i][j] = __builtin_amdgcn_mfma_f32_16x16x32_bf16(af[i], bfr[j], acc[i][j], 0, 0, 0);
    }

    #pragma unroll
    for (int i = 0; i < 4; i++) {
        #pragma unroll
        for (int j = 0; j < 4; j++) {
            #pragma unroll
            for (int r = 0; r < 4; r++) {
                int row = m0 + RW + i * 16 + quad * 4 + r;
                int col = n0 + CW + j * 16 + lr;
                float v = acc[i][j][r];
                size_t idx = (size_t)row * ldc + col;
                if constexpr (EPI == 0) {
                    if (col < 1024) v = v > 0.f ? v + 1.f : __expf(v);
                    else            v *= (1.0f / SEQ);
                    outb[idx] = f2bf(v);
                } else if constexpr (EPI == 1) {
                    outf[idx] = resid[idx] + v;
                } else if constexpr (EPI == 2) {
                    v += bias[col];
                    v = 0.5f * v * (1.f + erff(v * 0.70710678118f));
                    outb[idx] = f2bf(v);
                } else {
                    outf[idx] = outf[idx] + v + bias[col];
                }
            }
        }
    }
}

// ---------------- zero fill ----------------
__global__ __launch_bounds__(256) void zero_kernel(float* p, int n) {
    int i = blockIdx.x * 256 + threadIdx.x;
    if (i < n) p[i] = 0.f;
}

// ---------------- KV = sum_s K outer v ; Ksum = sum_s K. split over 8 seq chunks ----------------
__global__ __launch_bounds__(256) void kv_reduce(
    const u16* __restrict__ qkv, float* __restrict__ KV, float* __restrict__ Ksum)
{
    int bh = blockIdx.x;            // 0..127
    int b = bh >> 4, h = bh & 15;
    int chunk = blockIdx.y;         // 0..7
    int t = threadIdx.x;
    __shared__ float Ks[32 * 32];
    __shared__ float Vs[32 * 32];
    int d  = t & 31;
    int vd = (t >> 5) << 2;
    float a0 = 0.f, a1 = 0.f, a2 = 0.f, a3 = 0.f, ks = 0.f;
    const size_t base = (size_t)b * SEQ * 1536 + 512 + h * HD;  // K part
    int j   = t & 127;              // uint4 index within 32x32 tile
    int isV = t >> 7;               // threads 0-127: K tile, 128-255: V tile
    int sl  = j >> 2, cc = (j & 3) * 8;
    float* dst = (isV ? Vs : Ks) + sl * 32 + cc;
    for (int so = 0; so < 512; so += 32) {
        size_t gp = base + (size_t)(chunk * 512 + so + sl) * 1536 + cc + (isV ? 512 : 0);
        union { uint4 v; u16 u[8]; } uu;
        uu.v = *(const uint4*)(qkv + gp);
        float f[8];
        #pragma unroll
        for (int q = 0; q < 8; q++) f[q] = bf2f(uu.u[q]);
        __syncthreads();
        *(float4*)dst       = float4{f[0], f[1], f[2], f[3]};
        *(float4*)(dst + 4) = float4{f[4], f[5], f[6], f[7]};
        __syncthreads();
        #pragma unroll
        for (int s = 0; s < 32; s++) {
            float kvv = Ks[s * 32 + d];
            float4 vv = *(const float4*)(Vs + s * 32 + vd);
            a0 += kvv * vv.x; a1 += kvv * vv.y; a2 += kvv * vv.z; a3 += kvv * vv.w;
            ks += kvv;
        }
    }
    float* kvp = KV + (size_t)bh * 1024 + d * 32 + vd;
    atomicAdd(kvp + 0, a0);
    atomicAdd(kvp + 1, a1);
    atomicAdd(kvp + 2, a2);
    atomicAdd(kvp + 3, a3);
    if (t < 32) atomicAdd(Ksum + bh * 32 + t, ks);
}

// ---------------- msg = (Q . KV) * SEQ / (Q . Ksum + eps) ----------------
// KV columns in registers (reused across 128 rows); Q staged via LDS (broadcast reads).
__global__ __launch_bounds__(256) void msg_kernel(
    const u16* __restrict__ qkv, const float* __restrict__ KV,
    const float* __restrict__ Ksum, u16* __restrict__ msg)
{
    int blk = blockIdx.x;           // 256 blocks
    int b = blk >> 5;
    int r0 = (blk & 31) * 128;
    int t = threadIdx.x;
    int h = t >> 4;
    int vd = (t & 15) * 2;
    float kv0[32], kv1[32], ksr[32];
    const float* kvh = KV + ((size_t)b * 16 + h) * 1024;
    const float* ksh = Ksum + (b * 16 + h) * 32;
    #pragma unroll
    for (int d = 0; d < 32; d++) {
        kv0[d] = kvh[d * 32 + vd];
        kv1[d] = kvh[d * 32 + vd + 1];
        ksr[d] = ksh[d];
    }
    __shared__ u16 Qs[4 * 512];
    const int srr = t >> 6;          // staging: row in 4-group
    const int scc = (t & 63) * 8;    // 64 lanes x 8 shorts = 512 (full Q part)
    for (int rg = 0; rg < 128; rg += 4) {
        size_t row = (size_t)b * SEQ + r0 + rg;
        uint4 qv = *(const uint4*)(qkv + (row + srr) * 1536 + scc);
        __syncthreads();
        *(uint4*)(Qs + srr * 512 + scc) = qv;
        __syncthreads();
        #pragma unroll
        for (int r2 = 0; r2 < 4; r2++) {
            const u16* qp = Qs + r2 * 512 + h * HD;
            float q[32];
            #pragma unroll
            for (int i0 = 0; i0 < 32; i0 += 8) {
                union { uint4 v; u16 u[8]; } uu;
                uu.v = *(const uint4*)(qp + i0);
                #pragma unroll
                for (int jq = 0; jq < 8; jq++) q[i0 + jq] = bf2f(uu.u[jq]);
            }
            float zdot = 0.f, m0 = 0.f, m1 = 0.f;
            #pragma unroll
            for (int d = 0; d < 32; d++) {
                float qd = q[d];
                zdot += qd * ksr[d];
                m0   += qd * kv0[d];
                m1   += qd * kv1[d];
            }
            float z = (float)SEQ / (zdot + 1e-6f);
            unsigned pack = (unsigned)f2bf(m0 * z) | ((unsigned)f2bf(m1 * z) << 16);
            *(unsigned*)(msg + (row + r2) * C + h * HD + vd) = pack;
        }
    }
}

extern "C" void kernel_launch(void* const* d_in, const int* in_sizes, int n_in,
                              void* d_out, int out_size, void* d_ws, size_t ws_size,
                              hipStream_t stream) {
    const float* x     = (const float*)d_in[0];
    const float* Wq    = (const float*)d_in[1];
    const float* Wk    = (const float*)d_in[2];
    const float* Wv    = (const float*)d_in[3];
    const float* Wm    = (const float*)d_in[4];
    const float* W1    = (const float*)d_in[5];
    const float* b1    = (const float*)d_in[6];
    const float* W2    = (const float*)d_in[7];
    const float* b2    = (const float*)d_in[8];
    const float* g_att = (const float*)d_in[9];
    const float* b_att = (const float*)d_in[10];
    const float* g_ffn = (const float*)d_in[11];
    const float* b_ffn = (const float*)d_in[12];
    float* out = (float*)d_out;

    char* ws = (char*)d_ws;
    u16*   Wqkvt = (u16*)(ws);                    // 1.5 MB
    u16*   Wmt   = (u16*)(ws + 0x180000);         // 0.5 MB
    u16*   W1t   = (u16*)(ws + 0x200000);         // 0.5 MB
    u16*   W2t   = (u16*)(ws + 0x280000);         // 0.5 MB
    float* KV    = (float*)(ws + 0x300000);       // 512 KB
    float* Ksum  = (float*)(ws + 0x380000);       // 16 KB (contiguous after KV)
    u16*   hb    = (u16*)(ws + 0x400000);         // 32 MB (LN1 out; reused as msg)
    u16*   qkv   = (u16*)(ws + 0x2400000);        // 96 MB (reused: h2)
    u16*   h2    = qkv;                           // 32 MB
    u16*   f1    = (u16*)(ws + 0x4400000);        // 32 MB

    // 1. weights -> bf16 transposed (coalesced LDS-tile transpose)
    prep_weights<<<6 * 64, 256, 0, stream>>>(Wq, Wk, Wv, Wm, W1, W2,
                                             Wqkvt, Wmt, W1t, W2t);
    // 2. LN1
    ln_kernel<<<ROWS / 4, 256, 0, stream>>>(x, g_att, b_att, hb);
    // 3. qkv = h @ [Wq|Wk|Wv] with feature-map epilogue
    gemm_tile<0><<<dim3(12, 256), 256, 0, stream>>>(hb, Wqkvt, 512, 1536,
                                                    qkv, nullptr, nullptr, nullptr);
    // 4. zero KV+Ksum, then reduce
    zero_kernel<<<(128 * 1024 + 128 * 32 + 255) / 256, 256, 0, stream>>>(KV, 128 * 1024 + 128 * 32);
    kv_reduce<<<dim3(128, 8), 256, 0, stream>>>(qkv, KV, Ksum);
    // 5. msg
    msg_kernel<<<256, 256, 0, stream>>>(qkv, KV, Ksum, hb);
    // 6. x2 = x + msg @ Wm   (x2 lives in d_out)
    gemm_tile<1><<<dim3(4, 256), 256, 0, stream>>>(hb, Wmt, 512, 512,
                                                   nullptr, out, nullptr, x);
    // 7. LN2
    ln_kernel<<<ROWS / 4, 256, 0, stream>>>(out, g_ffn, b_ffn, h2);
    // 8. f1 = gelu(h2 @ W1 + b1)
    gemm_tile<2><<<dim3(4, 256), 256, 0, stream>>>(h2, W1t, 512, 512,
                                                   f1, nullptr, b1, nullptr);
    // 9. out = x2 + f1 @ W2 + b2   (in place on d_out)
    gemm_tile<3><<<dim3(4, 256), 256, 0, stream>>>(f1, W2t, 512, 512,
                                                   nullptr, out, b2, nullptr);
}

// Round 3
// 445.318 us; speedup vs baseline: 1.0722x; 1.0595x over previous
//
#include <hip/hip_runtime.h>
#include <hip/hip_bf16.h>
#include <math.h>

typedef unsigned short u16;
typedef __attribute__((ext_vector_type(8))) __bf16 bf16x8;
typedef __attribute__((ext_vector_type(4))) float floatx4;

#define SEQ   4096
#define BATCH 8
#define ROWS  32768   // BATCH*SEQ
#define C     512
#define NH    16
#define HD    32

__device__ inline u16 f2bf(float f) {
    union { float f; unsigned u; } v; v.f = f;
    unsigned r = (v.u + 0x7FFFu + ((v.u >> 16) & 1u)) >> 16;
    return (u16)r;
}
__device__ inline float bf2f(u16 h) {
    union { unsigned u; float f; } v; v.u = ((unsigned)h) << 16;
    return v.f;
}

// async global -> LDS, 16B per lane; lds ptr must be wave-uniform (HW adds lane*16)
__device__ inline void g2lds16(const u16* g, u16* l) {
    __builtin_amdgcn_global_load_lds((const __attribute__((address_space(1))) unsigned*)g,
                                     (__attribute__((address_space(3))) unsigned*)l, 16, 0, 0);
}

// ---------------- weight prep: fp32 (k,n) -> bf16 transposed (n,k), 64x64 LDS tiles ----------------
__global__ __launch_bounds__(256) void prep_weights(
    const float* __restrict__ Wq, const float* __restrict__ Wk,
    const float* __restrict__ Wv, const float* __restrict__ Wm,
    const float* __restrict__ W1, const float* __restrict__ W2,
    u16* __restrict__ Wqkvt, u16* __restrict__ Wmt,
    u16* __restrict__ W1t, u16* __restrict__ W2t)
{
    int blk = blockIdx.x;                 // 6 mats * 64 tiles
    int mat = blk >> 6;
    int tile = blk & 63;
    int k0 = (tile >> 3) * 64, n0 = (tile & 7) * 64;
    const float* src; u16* dst;
    switch (mat) {
        case 0: src = Wq; dst = Wqkvt;              break;
        case 1: src = Wk; dst = Wqkvt + 512*512;    break;
        case 2: src = Wv; dst = Wqkvt + 2*512*512;  break;
        case 3: src = Wm; dst = Wmt;                break;
        case 4: src = W1; dst = W1t;                break;
        default: src = W2; dst = W2t;               break;
    }
    __shared__ float ts[64][65];
    int t = threadIdx.x;
    #pragma unroll
    for (int i = 0; i < 16; i++) {
        int e = i * 256 + t;
        int kr = e >> 6, nc = e & 63;
        ts[kr][nc] = src[(size_t)(k0 + kr) * 512 + n0 + nc];   // coalesced 256B rows
    }
    __syncthreads();
    #pragma unroll
    for (int i = 0; i < 2; i++) {
        int e = i * 256 + t;                 // 512 chunks of 8
        int nr = e >> 3, kc0 = (e & 7) * 8;
        union { uint4 v; u16 u[8]; } o;
        #pragma unroll
        for (int q = 0; q < 8; q++) o.u[q] = f2bf(ts[kc0 + q][nr]);
        *(uint4*)(dst + (size_t)(n0 + nr) * 512 + k0 + kc0) = o.v;   // coalesced 16B stores
    }
}

// ---------------- layernorm: fp32 in -> bf16 out, one wave per row ----------------
__global__ __launch_bounds__(256) void ln_kernel(
    const float* __restrict__ in, const float* __restrict__ g,
    const float* __restrict__ b, u16* __restrict__ out)
{
    int row  = blockIdx.x * 4 + (threadIdx.x >> 6);
    int lane = threadIdx.x & 63;
    const float* p = in + (size_t)row * C + lane * 8;
    float4 v0 = *(const float4*)p;
    float4 v1 = *(const float4*)(p + 4);
    float s  = v0.x + v0.y + v0.z + v0.w + v1.x + v1.y + v1.z + v1.w;
    float s2 = v0.x*v0.x + v0.y*v0.y + v0.z*v0.z + v0.w*v0.w
             + v1.x*v1.x + v1.y*v1.y + v1.z*v1.z + v1.w*v1.w;
    #pragma unroll
    for (int off = 1; off < 64; off <<= 1) {
        s  += __shfl_xor(s, off);
        s2 += __shfl_xor(s2, off);
    }
    float mean = s * (1.f / C);
    float var  = s2 * (1.f / C) - mean * mean;
    float inv  = rsqrtf(var + 1e-6f);
    int c = lane * 8;
    float4 g0 = *(const float4*)(g + c), g1 = *(const float4*)(g + c + 4);
    float4 b0 = *(const float4*)(b + c), b1 = *(const float4*)(b + c + 4);
    union { uint4 v; u16 u[8]; } o;
    o.u[0] = f2bf((v0.x - mean) * inv * g0.x + b0.x);
    o.u[1] = f2bf((v0.y - mean) * inv * g0.y + b0.y);
    o.u[2] = f2bf((v0.z - mean) * inv * g0.z + b0.z);
    o.u[3] = f2bf((v0.w - mean) * inv * g0.w + b0.w);
    o.u[4] = f2bf((v1.x - mean) * inv * g1.x + b1.x);
    o.u[5] = f2bf((v1.y - mean) * inv * g1.y + b1.y);
    o.u[6] = f2bf((v1.z - mean) * inv * g1.z + b1.z);
    o.u[7] = f2bf((v1.w - mean) * inv * g1.w + b1.w);
    *(uint4*)(out + (size_t)row * C + c) = o.v;
}

// ---------------- bf16 MFMA GEMM, 128x128 tile, BK=64, global_load_lds + swizzled LDS ----------------
// A: M x K row-major bf16.  Bt: N x K row-major bf16.
// LDS tile 128 rows x 64 shorts, column chunks rotated by (row&7)*8 to kill bank conflicts:
//   LDS[r][c'] = G[r][ (((c'>>3) - (r&7)) & 7)*8 + (c'&7) ]
// EPI 0: qkv epilogue (elu+1 on cols<1024, /SEQ on v part) -> bf16
// EPI 1: out_f32 = resid + acc
// EPI 2: bf16 = gelu(acc + bias[col])
// EPI 3: out_f32 = out_f32(in place) + acc + bias[col]
template <int EPI>
__global__ __launch_bounds__(256, 2) void gemm_tile(
    const u16* __restrict__ A, const u16* __restrict__ Bt,
    int K, int ldc,
    u16* __restrict__ outb, float* __restrict__ outf,
    const float* __restrict__ bias, const float* __restrict__ resid)
{
    __shared__ u16 lsA[128 * 64];
    __shared__ u16 lsB[128 * 64];
    const int t = threadIdx.x;
    const int w = t >> 6, l = t & 63, lr = l & 15, quad = l >> 4;
    const int m0 = blockIdx.y * 128, n0 = blockIdx.x * 128;
    const int RW = (w >> 1) * 64, CW = (w & 1) * 64;

    floatx4 acc[4][4];
    #pragma unroll
    for (int i = 0; i < 4; i++)
        #pragma unroll
        for (int j = 0; j < 4; j++) { floatx4 z = {0.f, 0.f, 0.f, 0.f}; acc[i][j] = z; }

    // staging: wave w stages rows w*32 .. w*32+31 (4 chunks of 8 rows)
    // lane l -> row offset (l>>3), LDS cols (l&7)*8, global cols rotated by -(row&7)*8
    const int srow = w * 32 + (l >> 3);
    const int scol = (((l & 7) - (l >> 3)) & 7) * 8;      // row&7 == l>>3 here
    const u16* Ag = A  + (size_t)(m0 + srow) * K + scol;
    const u16* Bg = Bt + (size_t)(n0 + srow) * K + scol;
    u16* lAw = lsA + w * 2048;
    u16* lBw = lsB + w * 2048;

    for (int kk = 0; kk < K; kk += 64) {
        __syncthreads();                 // prior compute done before overwriting LDS
        #pragma unroll
        for (int c = 0; c < 4; c++) {
            g2lds16(Ag + (size_t)(c * 8) * K + kk, lAw + c * 512);
            g2lds16(Bg + (size_t)(c * 8) * K + kk, lBw + c * 512);
        }
        __syncthreads();                 // drain before reading LDS
        #pragma unroll
        for (int ks = 0; ks < 2; ks++) {
            bf16x8 af[4], bfr[4];
            const int m = ((ks * 4 + quad + (lr & 7)) & 7) * 8;  // un-rotated k column
            #pragma unroll
            for (int i = 0; i < 4; i++) {
                af[i]  = *(const bf16x8*)(lsA + (RW + i * 16 + lr) * 64 + m);
                bfr[i] = *(const bf16x8*)(lsB + (CW + i * 16 + lr) * 64 + m);
            }
            #pragma unroll
            for (int i = 0; i < 4; i++)
                #pragma unroll
                for (int j = 0; j < 4; j++)
                    acc[i][j] = __builtin_amdgcn_mfma_f32_16x16x32_bf16(af[i], bfr[j], acc[i][j], 0, 0, 0);
        }
    }

    #pragma unroll
    for (int i = 0; i < 4; i++) {
        #pragma unroll
        for (int j = 0; j < 4; j++) {
            #pragma unroll
            for (int r = 0; r < 4; r++) {
                int row = m0 + RW + i * 16 + quad * 4 + r;
                int col = n0 + CW + j * 16 + lr;
                float v = acc[i][j][r];
                size_t idx = (size_t)row * ldc + col;
                if constexpr (EPI == 0) {
                    if (col < 1024) v = v > 0.f ? v + 1.f : __expf(v);
                    else            v *= (1.0f / SEQ);
                    outb[idx] = f2bf(v);
                } else if constexpr (EPI == 1) {
                    outf[idx] = resid[idx] + v;
                } else if constexpr (EPI == 2) {
                    v += bias[col];
                    v = 0.5f * v * (1.f + erff(v * 0.70710678118f));
                    outb[idx] = f2bf(v);
                } else {
                    outf[idx] = outf[idx] + v + bias[col];
                }
            }
        }
    }
}

// ---------------- KV = sum_s K outer v ; Ksum = sum_s K. split over 16 seq chunks ----------------
__global__ __launch_bounds__(256) void kv_reduce(
    const u16* __restrict__ qkv, float* __restrict__ KV, float* __restrict__ Ksum)
{
    int bh = blockIdx.x;            // 0..127
    int b = bh >> 4, h = bh & 15;
    int chunk = blockIdx.y;         // 0..15 (256 seq rows each)
    int t = threadIdx.x;
    __shared__ float Ks[32 * 32];
    __shared__ float Vs[32 * 32];
    int d  = t & 31;
    int vd = (t >> 5) << 2;
    float a0 = 0.f, a1 = 0.f, a2 = 0.f, a3 = 0.f, ks = 0.f;
    const size_t base = (size_t)b * SEQ * 1536 + 512 + h * HD;  // K part
    int j   = t & 127;              // uint4 index within 32x32 tile
    int isV = t >> 7;               // threads 0-127: K tile, 128-255: V tile
    int sl  = j >> 2, cc = (j & 3) * 8;
    float* dst = (isV ? Vs : Ks) + sl * 32 + cc;
    for (int so = 0; so < 256; so += 32) {
        size_t gp = base + (size_t)(chunk * 256 + so + sl) * 1536 + cc + (isV ? 512 : 0);
        union { uint4 v; u16 u[8]; } uu;
        uu.v = *(const uint4*)(qkv + gp);
        float f[8];
        #pragma unroll
        for (int q = 0; q < 8; q++) f[q] = bf2f(uu.u[q]);
        __syncthreads();
        *(float4*)dst       = float4{f[0], f[1], f[2], f[3]};
        *(float4*)(dst + 4) = float4{f[4], f[5], f[6], f[7]};
        __syncthreads();
        #pragma unroll
        for (int s = 0; s < 32; s++) {
            float kvv = Ks[s * 32 + d];
            float4 vv = *(const float4*)(Vs + s * 32 + vd);
            a0 += kvv * vv.x; a1 += kvv * vv.y; a2 += kvv * vv.z; a3 += kvv * vv.w;
            ks += kvv;
        }
    }
    float* kvp = KV + (size_t)bh * 1024 + d * 32 + vd;
    atomicAdd(kvp + 0, a0);
    atomicAdd(kvp + 1, a1);
    atomicAdd(kvp + 2, a2);
    atomicAdd(kvp + 3, a3);
    if (t < 32) atomicAdd(Ksum + bh * 32 + t, ks);
}

// ---------------- msg = (Q . KV) * SEQ / (Q . Ksum + eps) ----------------
// KV columns in registers (reused across 32 rows); Q staged via LDS (broadcast reads).
__global__ __launch_bounds__(256) void msg_kernel(
    const u16* __restrict__ qkv, const float* __restrict__ KV,
    const float* __restrict__ Ksum, u16* __restrict__ msg)
{
    int blk = blockIdx.x;           // 1024 blocks
    int b = blk >> 7;
    int r0 = (blk & 127) * 32;
    int t = threadIdx.x;
    int h = t >> 4;
    int vd = (t & 15) * 2;
    float kv0[32], kv1[32], ksr[32];
    const float* kvh = KV + ((size_t)b * 16 + h) * 1024;
    const float* ksh = Ksum + (b * 16 + h) * 32;
    #pragma unroll
    for (int d = 0; d < 32; d++) {
        kv0[d] = kvh[d * 32 + vd];
        kv1[d] = kvh[d * 32 + vd + 1];
        ksr[d] = ksh[d];
    }
    __shared__ u16 Qs[4 * 512];
    const int srr = t >> 6;          // staging: row in 4-group
    const int scc = (t & 63) * 8;    // 64 lanes x 8 shorts = 512 (full Q part)
    for (int rg = 0; rg < 32; rg += 4) {
        size_t row = (size_t)b * SEQ + r0 + rg;
        uint4 qv = *(const uint4*)(qkv + (row + srr) * 1536 + scc);
        __syncthreads();
        *(uint4*)(Qs + srr * 512 + scc) = qv;
        __syncthreads();
        #pragma unroll
        for (int r2 = 0; r2 < 4; r2++) {
            const u16* qp = Qs + r2 * 512 + h * HD;
            float q[32];
            #pragma unroll
            for (int i0 = 0; i0 < 32; i0 += 8) {
                union { uint4 v; u16 u[8]; } uu;
                uu.v = *(const uint4*)(qp + i0);
                #pragma unroll
                for (int jq = 0; jq < 8; jq++) q[i0 + jq] = bf2f(uu.u[jq]);
            }
            float zdot = 0.f, m0 = 0.f, m1 = 0.f;
            #pragma unroll
            for (int d = 0; d < 32; d++) {
                float qd = q[d];
                zdot += qd * ksr[d];
                m0   += qd * kv0[d];
                m1   += qd * kv1[d];
            }
            float z = (float)SEQ / (zdot + 1e-6f);
            unsigned pack = (unsigned)f2bf(m0 * z) | ((unsigned)f2bf(m1 * z) << 16);
            *(unsigned*)(msg + (row + r2) * C + h * HD + vd) = pack;
        }
    }
}

extern "C" void kernel_launch(void* const* d_in, const int* in_sizes, int n_in,
                              void* d_out, int out_size, void* d_ws, size_t ws_size,
                              hipStream_t stream) {
    const float* x     = (const float*)d_in[0];
    const float* Wq    = (const float*)d_in[1];
    const float* Wk    = (const float*)d_in[2];
    const float* Wv    = (const float*)d_in[3];
    const float* Wm    = (const float*)d_in[4];
    const float* W1    = (const float*)d_in[5];
    const float* b1    = (const float*)d_in[6];
    const float* W2    = (const float*)d_in[7];
    const float* b2    = (const float*)d_in[8];
    const float* g_att = (const float*)d_in[9];
    const float* b_att = (const float*)d_in[10];
    const float* g_ffn = (const float*)d_in[11];
    const float* b_ffn = (const float*)d_in[12];
    float* out = (float*)d_out;

    char* ws = (char*)d_ws;
    u16*   Wqkvt = (u16*)(ws);                    // 1.5 MB
    u16*   Wmt   = (u16*)(ws + 0x180000);         // 0.5 MB
    u16*   W1t   = (u16*)(ws + 0x200000);         // 0.5 MB
    u16*   W2t   = (u16*)(ws + 0x280000);         // 0.5 MB
    float* KV    = (float*)(ws + 0x300000);       // 512 KB
    float* Ksum  = (float*)(ws + 0x380000);       // 16 KB (contiguous after KV)
    u16*   hb    = (u16*)(ws + 0x400000);         // 32 MB (LN1 out; reused as msg)
    u16*   qkv   = (u16*)(ws + 0x2400000);        // 96 MB (reused: h2)
    u16*   h2    = qkv;                           // 32 MB
    u16*   f1    = (u16*)(ws + 0x4400000);        // 32 MB

    // 1. weights -> bf16 transposed (coalesced LDS-tile transpose)
    prep_weights<<<6 * 64, 256, 0, stream>>>(Wq, Wk, Wv, Wm, W1, W2,
                                             Wqkvt, Wmt, W1t, W2t);
    // 2. LN1
    ln_kernel<<<ROWS / 4, 256, 0, stream>>>(x, g_att, b_att, hb);
    // 3. qkv = h @ [Wq|Wk|Wv] with feature-map epilogue
    gemm_tile<0><<<dim3(12, 256), 256, 0, stream>>>(hb, Wqkvt, 512, 1536,
                                                    qkv, nullptr, nullptr, nullptr);
    // 4. zero KV+Ksum (contiguous, 0x84000 bytes), then reduce
    hipMemsetAsync(KV, 0, (128 * 1024 + 128 * 32) * sizeof(float), stream);
    kv_reduce<<<dim3(128, 16), 256, 0, stream>>>(qkv, KV, Ksum);
    // 5. msg
    msg_kernel<<<1024, 256, 0, stream>>>(qkv, KV, Ksum, hb);
    // 6. x2 = x + msg @ Wm   (x2 lives in d_out)
    gemm_tile<1><<<dim3(4, 256), 256, 0, stream>>>(hb, Wmt, 512, 512,
                                                   nullptr, out, nullptr, x);
    // 7. LN2
    ln_kernel<<<ROWS / 4, 256, 0, stream>>>(out, g_ffn, b_ffn, h2);
    // 8. f1 = gelu(h2 @ W1 + b1)
    gemm_tile<2><<<dim3(4, 256), 256, 0, stream>>>(h2, W1t, 512, 512,
                                                   f1, nullptr, b1, nullptr);
    // 9. out = x2 + f1 @ W2 + b2   (in place on d_out)
    gemm_tile<3><<<dim3(4, 256), 256, 0, stream>>>(f1, W2t, 512, 512,
                                                   nullptr, out, b2, nullptr);
}

// Round 6
// 412.359 us; speedup vs baseline: 1.1579x; 1.0799x over previous
//
#include <hip/hip_runtime.h>
#include <hip/hip_bf16.h>
#include <math.h>

typedef unsigned short u16;
typedef __attribute__((ext_vector_type(8))) __bf16 bf16x8;
typedef __attribute__((ext_vector_type(4))) float floatx4;

#define SEQ   4096
#define BATCH 8
#define ROWS  32768   // BATCH*SEQ
#define C     512
#define NH    16
#define HD    32

__device__ inline u16 f2bf(float f) {
    union { float f; unsigned u; } v; v.f = f;
    unsigned r = (v.u + 0x7FFFu + ((v.u >> 16) & 1u)) >> 16;
    return (u16)r;
}
__device__ inline float bf2f(u16 h) {
    union { unsigned u; float f; } v; v.u = ((unsigned)h) << 16;
    return v.f;
}

// async global -> LDS, 16B per lane; lds ptr must be wave-uniform (HW adds lane*16)
__device__ inline void g2lds16(const u16* g, u16* l) {
    __builtin_amdgcn_global_load_lds((const __attribute__((address_space(1))) unsigned*)g,
                                     (__attribute__((address_space(3))) unsigned*)l, 16, 0, 0);
}

// ---------------- weight prep: fp32 (k,n) -> bf16 transposed (n,k), 64x64 LDS tiles ----------------
__global__ __launch_bounds__(256) void prep_weights(
    const float* __restrict__ Wq, const float* __restrict__ Wk,
    const float* __restrict__ Wv, const float* __restrict__ Wm,
    const float* __restrict__ W1, const float* __restrict__ W2,
    u16* __restrict__ Wqkvt, u16* __restrict__ Wmt,
    u16* __restrict__ W1t, u16* __restrict__ W2t)
{
    int blk = blockIdx.x;                 // 6 mats * 64 tiles
    int mat = blk >> 6;
    int tile = blk & 63;
    int k0 = (tile >> 3) * 64, n0 = (tile & 7) * 64;
    const float* src; u16* dst;
    switch (mat) {
        case 0: src = Wq; dst = Wqkvt;              break;
        case 1: src = Wk; dst = Wqkvt + 512*512;    break;
        case 2: src = Wv; dst = Wqkvt + 2*512*512;  break;
        case 3: src = Wm; dst = Wmt;                break;
        case 4: src = W1; dst = W1t;                break;
        default: src = W2; dst = W2t;               break;
    }
    __shared__ float ts[64][65];
    int t = threadIdx.x;
    #pragma unroll
    for (int i = 0; i < 16; i++) {
        int e = i * 256 + t;
        int kr = e >> 6, nc = e & 63;
        ts[kr][nc] = src[(size_t)(k0 + kr) * 512 + n0 + nc];   // coalesced 256B rows
    }
    __syncthreads();
    #pragma unroll
    for (int i = 0; i < 2; i++) {
        int e = i * 256 + t;                 // 512 chunks of 8
        int nr = e >> 3, kc0 = (e & 7) * 8;
        union { uint4 v; u16 u[8]; } o;
        #pragma unroll
        for (int q = 0; q < 8; q++) o.u[q] = f2bf(ts[kc0 + q][nr]);
        *(uint4*)(dst + (size_t)(n0 + nr) * 512 + k0 + kc0) = o.v;   // coalesced 16B stores
    }
}

// ---------------- layernorm: fp32 in -> bf16 out, one wave per row ----------------
__global__ __launch_bounds__(256) void ln_kernel(
    const float* __restrict__ in, const float* __restrict__ g,
    const float* __restrict__ b, u16* __restrict__ out)
{
    int row  = blockIdx.x * 4 + (threadIdx.x >> 6);
    int lane = threadIdx.x & 63;
    const float* p = in + (size_t)row * C + lane * 8;
    float4 v0 = *(const float4*)p;
    float4 v1 = *(const float4*)(p + 4);
    float s  = v0.x + v0.y + v0.z + v0.w + v1.x + v1.y + v1.z + v1.w;
    float s2 = v0.x*v0.x + v0.y*v0.y + v0.z*v0.z + v0.w*v0.w
             + v1.x*v1.x + v1.y*v1.y + v1.z*v1.z + v1.w*v1.w;
    #pragma unroll
    for (int off = 1; off < 64; off <<= 1) {
        s  += __shfl_xor(s, off);
        s2 += __shfl_xor(s2, off);
    }
    float mean = s * (1.f / C);
    float var  = s2 * (1.f / C) - mean * mean;
    float inv  = rsqrtf(var + 1e-6f);
    int c = lane * 8;
    float4 g0 = *(const float4*)(g + c), g1 = *(const float4*)(g + c + 4);
    float4 b0 = *(const float4*)(b + c), b1 = *(const float4*)(b + c + 4);
    union { uint4 v; u16 u[8]; } o;
    o.u[0] = f2bf((v0.x - mean) * inv * g0.x + b0.x);
    o.u[1] = f2bf((v0.y - mean) * inv * g0.y + b0.y);
    o.u[2] = f2bf((v0.z - mean) * inv * g0.z + b0.z);
    o.u[3] = f2bf((v0.w - mean) * inv * g0.w + b0.w);
    o.u[4] = f2bf((v1.x - mean) * inv * g1.x + b1.x);
    o.u[5] = f2bf((v1.y - mean) * inv * g1.y + b1.y);
    o.u[6] = f2bf((v1.z - mean) * inv * g1.z + b1.z);
    o.u[7] = f2bf((v1.w - mean) * inv * g1.w + b1.w);
    *(uint4*)(out + (size_t)row * C + c) = o.v;
}

// ---------------- bf16 MFMA GEMM, 128x128 tile, BK=64, global_load_lds + swizzled LDS ----------------
template <int EPI>
__global__ __launch_bounds__(256, 2) void gemm_tile(
    const u16* __restrict__ A, const u16* __restrict__ Bt,
    int K, int ldc,
    u16* __restrict__ outb, float* __restrict__ outf,
    const float* __restrict__ bias, const float* __restrict__ resid)
{
    __shared__ u16 lsA[128 * 64];
    __shared__ u16 lsB[128 * 64];
    const int t = threadIdx.x;
    const int w = t >> 6, l = t & 63, lr = l & 15, quad = l >> 4;
    const int m0 = blockIdx.y * 128, n0 = blockIdx.x * 128;
    const int RW = (w >> 1) * 64, CW = (w & 1) * 64;

    floatx4 acc[4][4];
    #pragma unroll
    for (int i = 0; i < 4; i++)
        #pragma unroll
        for (int j = 0; j < 4; j++) { floatx4 z = {0.f, 0.f, 0.f, 0.f}; acc[i][j] = z; }

    const int srow = w * 32 + (l >> 3);
    const int scol = (((l & 7) - (l >> 3)) & 7) * 8;      // row&7 == l>>3 here
    const u16* Ag = A  + (size_t)(m0 + srow) * K + scol;
    const u16* Bg = Bt + (size_t)(n0 + srow) * K + scol;
    u16* lAw = lsA + w * 2048;
    u16* lBw = lsB + w * 2048;

    for (int kk = 0; kk < K; kk += 64) {
        __syncthreads();
        #pragma unroll
        for (int c = 0; c < 4; c++) {
            g2lds16(Ag + (size_t)(c * 8) * K + kk, lAw + c * 512);
            g2lds16(Bg + (size_t)(c * 8) * K + kk, lBw + c * 512);
        }
        __syncthreads();
        #pragma unroll
        for (int ks = 0; ks < 2; ks++) {
            bf16x8 af[4], bfr[4];
            const int m = ((ks * 4 + quad + (lr & 7)) & 7) * 8;  // un-rotated k column
            #pragma unroll
            for (int i = 0; i < 4; i++) {
                af[i]  = *(const bf16x8*)(lsA + (RW + i * 16 + lr) * 64 + m);
                bfr[i] = *(const bf16x8*)(lsB + (CW + i * 16 + lr) * 64 + m);
            }
            #pragma unroll
            for (int i = 0; i < 4; i++)
                #pragma unroll
                for (int j = 0; j < 4; j++)
                    acc[i][j] = __builtin_amdgcn_mfma_f32_16x16x32_bf16(af[i], bfr[j], acc[i][j], 0, 0, 0);
        }
    }

    #pragma unroll
    for (int i = 0; i < 4; i++) {
        #pragma unroll
        for (int j = 0; j < 4; j++) {
            #pragma unroll
            for (int r = 0; r < 4; r++) {
                int row = m0 + RW + i * 16 + quad * 4 + r;
                int col = n0 + CW + j * 16 + lr;
                float v = acc[i][j][r];
                size_t idx = (size_t)row * ldc + col;
                if constexpr (EPI == 0) {
                    if (col < 1024) v = v > 0.f ? v + 1.f : __expf(v);
                    else            v *= (1.0f / SEQ);
                    outb[idx] = f2bf(v);
                } else if constexpr (EPI == 1) {
                    outf[idx] = resid[idx] + v;
                } else if constexpr (EPI == 2) {
                    v += bias[col];
                    v = 0.5f * v * (1.f + erff(v * 0.70710678118f));
                    outb[idx] = f2bf(v);
                } else {
                    outf[idx] = outf[idx] + v + bias[col];
                }
            }
        }
    }
}

// ---------------- KV partials via MFMA: per-wave private LDS tiles, no atomics ----------------
// Block = (bh, 512-seq chunk); wave w handles 128 seq rows in 4 steps of 32.
// KV[d,e] = sum_s K[s,d]*V[s,e]: 2x2 of 16x16x32 MFMAs; s-major -> k-packed transpose via
// scalar LDS gathers; staging chunk-rotated by (s>>3)&3 to reduce gather conflicts.
__global__ __launch_bounds__(256) void kv_reduce(
    const u16* __restrict__ qkv, float* __restrict__ Pkv, float* __restrict__ PKsum)
{
    const int bh = blockIdx.x;            // 0..127
    const int b = bh >> 4, h = bh & 15;
    const int chunk = blockIdx.y;         // 0..7
    const int t = threadIdx.x;
    const int w = t >> 6, l = t & 63, lr = l & 15, quad = l >> 4;
    __shared__ u16 lds[4 * 2 * 2048];     // [wave][buf][K 1024 | V 1024] = 32 KB

    const int sbase = chunk * 512 + w * 128;
    const u16* qbase = qkv + (size_t)b * SEQ * 1536 + 512 + h * HD;  // K part; V = +512

    // staging lane map: tile-local u16 idx = instr*512 + l*8 -> row sl, chunk cl=(l&3)
    // global chunk fetched = (cl + (sl>>3)) & 3  (rotation swizzle)
    const int sl0 = l >> 2;               // rows 0..15 (instr 0)
    const int sl1 = 16 + sl0;             // rows 16..31 (instr 1)
    const int cl  = l & 3;
    const int cg0 = (cl + (sl0 >> 3)) & 3;
    const int cg1 = (cl + (sl1 >> 3)) & 3;
    const int gof0 = sl0 * 1536 + cg0 * 8;
    const int gof1 = sl1 * 1536 + cg1 * 8;

    u16* myl = lds + w * 4096;

    // fragment gather offsets (tile-local): element j at off + j*32; un-rotate chunk
    const int offA0 = quad * 256 + ((((lr >> 3) + 0) - quad) & 3) * 8 + (lr & 7);  // d 0..15
    const int offA1 = quad * 256 + ((((lr >> 3) + 2) - quad) & 3) * 8 + (lr & 7);  // d 16..31

    floatx4 a00 = {0,0,0,0}, a01 = {0,0,0,0}, a10 = {0,0,0,0}, a11 = {0,0,0,0};
    float ks0 = 0.f, ks1 = 0.f;

    // prologue: stage buf 0
    {
        const u16* gK = qbase + (size_t)sbase * 1536;
        g2lds16(gK + gof0,       myl);
        g2lds16(gK + gof1,       myl + 512);
        g2lds16(gK + 512 + gof0, myl + 1024);
        g2lds16(gK + 512 + gof1, myl + 1536);
    }
    #pragma unroll
    for (int st = 0; st < 4; st++) {
        if (st < 3) {                      // prefetch next buf before the drain
            const u16* gK = qbase + (size_t)(sbase + (st + 1) * 32) * 1536;
            u16* nl = myl + ((st + 1) & 1) * 2048;
            g2lds16(gK + gof0,       nl);
            g2lds16(gK + gof1,       nl + 512);
            g2lds16(gK + 512 + gof0, nl + 1024);
            g2lds16(gK + 512 + gof1, nl + 1536);
        }
        __syncthreads();                   // vmcnt(0) drain, compiler-safe fence
        const u16* lK = myl + (st & 1) * 2048;
        const u16* lV = lK + 1024;
        union { bf16x8 v; u16 u[8]; } fa0, fa1, fb0, fb1;
        #pragma unroll
        for (int j = 0; j < 8; j++) {
            fa0.u[j] = lK[offA0 + j * 32];
            fa1.u[j] = lK[offA1 + j * 32];
            fb0.u[j] = lV[offA0 + j * 32];
            fb1.u[j] = lV[offA1 + j * 32];
        }
        #pragma unroll
        for (int j = 0; j < 8; j++) { ks0 += bf2f(fa0.u[j]); ks1 += bf2f(fa1.u[j]); }
        a00 = __builtin_amdgcn_mfma_f32_16x16x32_bf16(fa0.v, fb0.v, a00, 0, 0, 0);
        a01 = __builtin_amdgcn_mfma_f32_16x16x32_bf16(fa0.v, fb1.v, a01, 0, 0, 0);
        a10 = __builtin_amdgcn_mfma_f32_16x16x32_bf16(fa1.v, fb0.v, a10, 0, 0, 0);
        a11 = __builtin_amdgcn_mfma_f32_16x16x32_bf16(fa1.v, fb1.v, a11, 0, 0, 0);
    }

    // write per-wave partial: p = bh*32 + chunk*4 + w
    const int p = bh * 32 + chunk * 4 + w;
    float* dst = Pkv + (size_t)p * 1024;
    floatx4 accs[2][2] = {{a00, a01}, {a10, a11}};
    #pragma unroll
    for (int i = 0; i < 2; i++)
        #pragma unroll
        for (int j = 0; j < 2; j++)
            #pragma unroll
            for (int r = 0; r < 4; r++)
                dst[(i * 16 + quad * 4 + r) * 32 + j * 16 + lr] = accs[i][j][r];

    float k0 = ks0 + __shfl_xor(ks0, 16); k0 += __shfl_xor(k0, 32);
    float k1 = ks1 + __shfl_xor(ks1, 16); k1 += __shfl_xor(k1, 32);
    if (quad == 0) {
        PKsum[p * 32 + lr]      = k0;
        PKsum[p * 32 + 16 + lr] = k1;
    }
}

// ---------------- final reduce: KV[bh][1024] = sum of 32 partials; Ksum likewise ----------------
__global__ __launch_bounds__(256) void kv_final(
    const float* __restrict__ Pkv, const float* __restrict__ PKsum,
    float* __restrict__ KV, float* __restrict__ Ksum)
{
    const int bh = blockIdx.x;
    const int t = threadIdx.x;
    float a0 = 0.f, a1 = 0.f, a2 = 0.f, a3 = 0.f;
    for (int p = 0; p < 32; p++) {
        const float* src = Pkv + ((size_t)bh * 32 + p) * 1024;
        a0 += src[t];
        a1 += src[t + 256];
        a2 += src[t + 512];
        a3 += src[t + 768];
    }
    float* dst = KV + (size_t)bh * 1024;
    dst[t] = a0; dst[t + 256] = a1; dst[t + 512] = a2; dst[t + 768] = a3;
    if (t < 32) {
        float s = 0.f;
        for (int p = 0; p < 32; p++) s += PKsum[(bh * 32 + p) * 32 + t];
        Ksum[bh * 32 + t] = s;
    }
}

// ---------------- msg = (Q . KV) * SEQ / (Q . Ksum + eps) ----------------
__global__ __launch_bounds__(256) void msg_kernel(
    const u16* __restrict__ qkv, const float* __restrict__ KV,
    const float* __restrict__ Ksum, u16* __restrict__ msg)
{
    int blk = blockIdx.x;           // 1024 blocks
    int b = blk >> 7;
    int r0 = (blk & 127) * 32;
    int t = threadIdx.x;
    int h = t >> 4;
    int vd = (t & 15) * 2;
    float kv0[32], kv1[32], ksr[32];
    const float* kvh = KV + ((size_t)b * 16 + h) * 1024;
    const float* ksh = Ksum + (b * 16 + h) * 32;
    #pragma unroll
    for (int d = 0; d < 32; d++) {
        kv0[d] = kvh[d * 32 + vd];
        kv1[d] = kvh[d * 32 + vd + 1];
        ksr[d] = ksh[d];
    }
    __shared__ u16 Qs[4 * 512];
    const int srr = t >> 6;
    const int scc = (t & 63) * 8;
    for (int rg = 0; rg < 32; rg += 4) {
        size_t row = (size_t)b * SEQ + r0 + rg;
        uint4 qv = *(const uint4*)(qkv + (row + srr) * 1536 + scc);
        __syncthreads();
        *(uint4*)(Qs + srr * 512 + scc) = qv;
        __syncthreads();
        #pragma unroll
        for (int r2 = 0; r2 < 4; r2++) {
            const u16* qp = Qs + r2 * 512 + h * HD;
            float q[32];
            #pragma unroll
            for (int i0 = 0; i0 < 32; i0 += 8) {
                union { uint4 v; u16 u[8]; } uu;
                uu.v = *(const uint4*)(qp + i0);
                #pragma unroll
                for (int jq = 0; jq < 8; jq++) q[i0 + jq] = bf2f(uu.u[jq]);
            }
            float zdot = 0.f, m0 = 0.f, m1 = 0.f;
            #pragma unroll
            for (int d = 0; d < 32; d++) {
                float qd = q[d];
                zdot += qd * ksr[d];
                m0   += qd * kv0[d];
                m1   += qd * kv1[d];
            }
            float z = (float)SEQ / (zdot + 1e-6f);
            unsigned pack = (unsigned)f2bf(m0 * z) | ((unsigned)f2bf(m1 * z) << 16);
            *(unsigned*)(msg + (row + r2) * C + h * HD + vd) = pack;
        }
    }
}

extern "C" void kernel_launch(void* const* d_in, const int* in_sizes, int n_in,
                              void* d_out, int out_size, void* d_ws, size_t ws_size,
                              hipStream_t stream) {
    const float* x     = (const float*)d_in[0];
    const float* Wq    = (const float*)d_in[1];
    const float* Wk    = (const float*)d_in[2];
    const float* Wv    = (const float*)d_in[3];
    const float* Wm    = (const float*)d_in[4];
    const float* W1    = (const float*)d_in[5];
    const float* b1    = (const float*)d_in[6];
    const float* W2    = (const float*)d_in[7];
    const float* b2    = (const float*)d_in[8];
    const float* g_att = (const float*)d_in[9];
    const float* b_att = (const float*)d_in[10];
    const float* g_ffn = (const float*)d_in[11];
    const float* b_ffn = (const float*)d_in[12];
    float* out = (float*)d_out;

    // Workspace map (live ranges disjoint in time):
    //   [0x000000, 0x300000)  weights bf16 (persistent all steps)
    //   [0x300000, 0x380000)  KV        (steps 4.5-5)
    //   [0x380000, 0x384000)  Ksum      (steps 4.5-5)
    //   [0x400000, 0x2400000) hb: LN1 out (steps 2-3); Pkv+PKsum (steps 4-4.5,
    //                         hb dead then); msg (steps 5-6)
    //   [0x2400000, 0x8400000) qkv 96MB (steps 3-5); h2 aliases base (7-8);
    //                         f1 at +0x2000000 (8-9, qkv dead)
    char* ws = (char*)d_ws;
    u16*   Wqkvt = (u16*)(ws);                    // 1.5 MB
    u16*   Wmt   = (u16*)(ws + 0x180000);         // 0.5 MB
    u16*   W1t   = (u16*)(ws + 0x200000);         // 0.5 MB
    u16*   W2t   = (u16*)(ws + 0x280000);         // 0.5 MB
    float* KV    = (float*)(ws + 0x300000);       // 512 KB
    float* Ksum  = (float*)(ws + 0x380000);       // 16 KB
    u16*   hb    = (u16*)(ws + 0x400000);         // 32 MB (LN1 out; reused as msg)
    float* Pkv   = (float*)(ws + 0x400000);       // 16 MB, aliases hb (hb dead in step 4)
    float* PKsum = (float*)(ws + 0x1400000);      // 512 KB
    u16*   qkv   = (u16*)(ws + 0x2400000);        // 96 MB
    u16*   h2    = qkv;                           // 32 MB (qkv dead after step 5)
    u16*   f1    = (u16*)(ws + 0x4400000);        // 32 MB (in qkv tail, dead by step 8)

    // 1. weights -> bf16 transposed
    prep_weights<<<6 * 64, 256, 0, stream>>>(Wq, Wk, Wv, Wm, W1, W2,
                                             Wqkvt, Wmt, W1t, W2t);
    // 2. LN1
    ln_kernel<<<ROWS / 4, 256, 0, stream>>>(x, g_att, b_att, hb);
    // 3. qkv = h @ [Wq|Wk|Wv] with feature-map epilogue
    gemm_tile<0><<<dim3(12, 256), 256, 0, stream>>>(hb, Wqkvt, 512, 1536,
                                                    qkv, nullptr, nullptr, nullptr);
    // 4. KV/Ksum: MFMA partials + final reduce (no atomics, no memset)
    kv_reduce<<<dim3(128, 8), 256, 0, stream>>>(qkv, Pkv, PKsum);
    kv_final<<<128, 256, 0, stream>>>(Pkv, PKsum, KV, Ksum);
    // 5. msg (overwrites hb region - Pkv already consumed)
    msg_kernel<<<1024, 256, 0, stream>>>(qkv, KV, Ksum, hb);
    // 6. x2 = x + msg @ Wm   (x2 lives in d_out)
    gemm_tile<1><<<dim3(4, 256), 256, 0, stream>>>(hb, Wmt, 512, 512,
                                                   nullptr, out, nullptr, x);
    // 7. LN2
    ln_kernel<<<ROWS / 4, 256, 0, stream>>>(out, g_ffn, b_ffn, h2);
    // 8. f1 = gelu(h2 @ W1 + b1)
    gemm_tile<2><<<dim3(4, 256), 256, 0, stream>>>(h2, W1t, 512, 512,
                                                   f1, nullptr, b1, nullptr);
    // 9. out = x2 + f1 @ W2 + b2   (in place on d_out)
    gemm_tile<3><<<dim3(4, 256), 256, 0, stream>>>(f1, W2t, 512, 512,
                                                   nullptr, out, b2, nullptr);
}

// Round 7
// 396.878 us; speedup vs baseline: 1.2030x; 1.0390x over previous
//
#include <hip/hip_runtime.h>
#include <hip/hip_bf16.h>
#include <math.h>

typedef unsigned short u16;
typedef __attribute__((ext_vector_type(8))) __bf16 bf16x8;
typedef __attribute__((ext_vector_type(4))) float floatx4;

#define SEQ   4096
#define BATCH 8
#define ROWS  32768   // BATCH*SEQ
#define C     512
#define NH    16
#define HD    32

__device__ inline u16 f2bf(float f) {
    union { float f; unsigned u; } v; v.f = f;
    unsigned r = (v.u + 0x7FFFu + ((v.u >> 16) & 1u)) >> 16;
    return (u16)r;
}
__device__ inline float bf2f(u16 h) {
    union { unsigned u; float f; } v; v.u = ((unsigned)h) << 16;
    return v.f;
}

// async global -> LDS, 16B per lane; lds ptr must be wave-uniform (HW adds lane*16)
__device__ inline void g2lds16(const u16* g, u16* l) {
    __builtin_amdgcn_global_load_lds((const __attribute__((address_space(1))) unsigned*)g,
                                     (__attribute__((address_space(3))) unsigned*)l, 16, 0, 0);
}

// ---------------- weight prep: fp32 (k,n) -> bf16 transposed (n,k), 64x64 LDS tiles ----------------
__global__ __launch_bounds__(256) void prep_weights(
    const float* __restrict__ Wq, const float* __restrict__ Wk,
    const float* __restrict__ Wv, const float* __restrict__ Wm,
    const float* __restrict__ W1, const float* __restrict__ W2,
    u16* __restrict__ Wqkvt, u16* __restrict__ Wmt,
    u16* __restrict__ W1t, u16* __restrict__ W2t)
{
    int blk = blockIdx.x;                 // 6 mats * 64 tiles
    int mat = blk >> 6;
    int tile = blk & 63;
    int k0 = (tile >> 3) * 64, n0 = (tile & 7) * 64;
    const float* src; u16* dst;
    switch (mat) {
        case 0: src = Wq; dst = Wqkvt;              break;
        case 1: src = Wk; dst = Wqkvt + 512*512;    break;
        case 2: src = Wv; dst = Wqkvt + 2*512*512;  break;
        case 3: src = Wm; dst = Wmt;                break;
        case 4: src = W1; dst = W1t;                break;
        default: src = W2; dst = W2t;               break;
    }
    __shared__ float ts[64][65];
    int t = threadIdx.x;
    #pragma unroll
    for (int i = 0; i < 16; i++) {
        int e = i * 256 + t;
        int kr = e >> 6, nc = e & 63;
        ts[kr][nc] = src[(size_t)(k0 + kr) * 512 + n0 + nc];   // coalesced 256B rows
    }
    __syncthreads();
    #pragma unroll
    for (int i = 0; i < 2; i++) {
        int e = i * 256 + t;                 // 512 chunks of 8
        int nr = e >> 3, kc0 = (e & 7) * 8;
        union { uint4 v; u16 u[8]; } o;
        #pragma unroll
        for (int q = 0; q < 8; q++) o.u[q] = f2bf(ts[kc0 + q][nr]);
        *(uint4*)(dst + (size_t)(n0 + nr) * 512 + k0 + kc0) = o.v;   // coalesced 16B stores
    }
}

// ---------------- layernorm: fp32 in -> bf16 out, one wave per row ----------------
__global__ __launch_bounds__(256) void ln_kernel(
    const float* __restrict__ in, const float* __restrict__ g,
    const float* __restrict__ b, u16* __restrict__ out)
{
    int row  = blockIdx.x * 4 + (threadIdx.x >> 6);
    int lane = threadIdx.x & 63;
    const float* p = in + (size_t)row * C + lane * 8;
    float4 v0 = *(const float4*)p;
    float4 v1 = *(const float4*)(p + 4);
    float s  = v0.x + v0.y + v0.z + v0.w + v1.x + v1.y + v1.z + v1.w;
    float s2 = v0.x*v0.x + v0.y*v0.y + v0.z*v0.z + v0.w*v0.w
             + v1.x*v1.x + v1.y*v1.y + v1.z*v1.z + v1.w*v1.w;
    #pragma unroll
    for (int off = 1; off < 64; off <<= 1) {
        s  += __shfl_xor(s, off);
        s2 += __shfl_xor(s2, off);
    }
    float mean = s * (1.f / C);
    float var  = s2 * (1.f / C) - mean * mean;
    float inv  = rsqrtf(var + 1e-6f);
    int c = lane * 8;
    float4 g0 = *(const float4*)(g + c), g1 = *(const float4*)(g + c + 4);
    float4 b0 = *(const float4*)(b + c), b1 = *(const float4*)(b + c + 4);
    union { uint4 v; u16 u[8]; } o;
    o.u[0] = f2bf((v0.x - mean) * inv * g0.x + b0.x);
    o.u[1] = f2bf((v0.y - mean) * inv * g0.y + b0.y);
    o.u[2] = f2bf((v0.z - mean) * inv * g0.z + b0.z);
    o.u[3] = f2bf((v0.w - mean) * inv * g0.w + b0.w);
    o.u[4] = f2bf((v1.x - mean) * inv * g1.x + b1.x);
    o.u[5] = f2bf((v1.y - mean) * inv * g1.y + b1.y);
    o.u[6] = f2bf((v1.z - mean) * inv * g1.z + b1.z);
    o.u[7] = f2bf((v1.w - mean) * inv * g1.w + b1.w);
    *(uint4*)(out + (size_t)row * C + c) = o.v;
}

// ---------------- bf16 MFMA GEMM, 128x128 tile, BK=64, global_load_lds + swizzled LDS ------------
// XCD-aware tile swizzle: linear grid; block g -> XCD g&7 (round-robin dispatch heuristic).
// Each XCD owns a 32-y-tile A panel (4 MB = one XCD L2) and sweeps x within it, so A is
// HBM-fetched ~once and staging loads become L2 hits (shorter vmcnt drains).
template <int EPI>
__global__ __launch_bounds__(256, 2) void gemm_tile(
    const u16* __restrict__ A, const u16* __restrict__ Bt,
    int K, int ldc, int nyt,
    u16* __restrict__ outb, float* __restrict__ outf,
    const float* __restrict__ bias, const float* __restrict__ resid)
{
    __shared__ u16 lsA[128 * 64];
    __shared__ u16 lsB[128 * 64];
    const int t = threadIdx.x;
    const int w = t >> 6, l = t & 63, lr = l & 15, quad = l >> 4;
    // tile swizzle
    const int g = blockIdx.x;
    const int xcd = g & 7;
    const int q = g >> 3;
    const int per = nyt >> 3;            // y-tiles per XCD panel
    const int ty = xcd * per + (q % per);
    const int tx = q / per;
    const int m0 = ty * 128, n0 = tx * 128;
    const int RW = (w >> 1) * 64, CW = (w & 1) * 64;

    floatx4 acc[4][4];
    #pragma unroll
    for (int i = 0; i < 4; i++)
        #pragma unroll
        for (int j = 0; j < 4; j++) { floatx4 z = {0.f, 0.f, 0.f, 0.f}; acc[i][j] = z; }

    const int srow = w * 32 + (l >> 3);
    const int scol = (((l & 7) - (l >> 3)) & 7) * 8;      // row&7 == l>>3 here
    const u16* Ag = A  + (size_t)(m0 + srow) * K + scol;
    const u16* Bg = Bt + (size_t)(n0 + srow) * K + scol;
    u16* lAw = lsA + w * 2048;
    u16* lBw = lsB + w * 2048;

    for (int kk = 0; kk < K; kk += 64) {
        __syncthreads();
        #pragma unroll
        for (int c = 0; c < 4; c++) {
            g2lds16(Ag + (size_t)(c * 8) * K + kk, lAw + c * 512);
            g2lds16(Bg + (size_t)(c * 8) * K + kk, lBw + c * 512);
        }
        __syncthreads();
        #pragma unroll
        for (int ks = 0; ks < 2; ks++) {
            bf16x8 af[4], bfr[4];
            const int m = ((ks * 4 + quad + (lr & 7)) & 7) * 8;  // un-rotated k column
            #pragma unroll
            for (int i = 0; i < 4; i++) {
                af[i]  = *(const bf16x8*)(lsA + (RW + i * 16 + lr) * 64 + m);
                bfr[i] = *(const bf16x8*)(lsB + (CW + i * 16 + lr) * 64 + m);
            }
            #pragma unroll
            for (int i = 0; i < 4; i++)
                #pragma unroll
                for (int j = 0; j < 4; j++)
                    acc[i][j] = __builtin_amdgcn_mfma_f32_16x16x32_bf16(af[i], bfr[j], acc[i][j], 0, 0, 0);
        }
    }

    #pragma unroll
    for (int i = 0; i < 4; i++) {
        #pragma unroll
        for (int j = 0; j < 4; j++) {
            #pragma unroll
            for (int r = 0; r < 4; r++) {
                int row = m0 + RW + i * 16 + quad * 4 + r;
                int col = n0 + CW + j * 16 + lr;
                float v = acc[i][j][r];
                size_t idx = (size_t)row * ldc + col;
                if constexpr (EPI == 0) {
                    if (col < 1024) v = v > 0.f ? v + 1.f : __expf(v);
                    else            v *= (1.0f / SEQ);
                    outb[idx] = f2bf(v);
                } else if constexpr (EPI == 1) {
                    outf[idx] = resid[idx] + v;
                } else if constexpr (EPI == 2) {
                    v += bias[col];
                    v = 0.5f * v * (1.f + erff(v * 0.70710678118f));
                    outb[idx] = f2bf(v);
                } else {
                    outf[idx] = outf[idx] + v + bias[col];
                }
            }
        }
    }
}

// ---------------- KV partials via MFMA: per-wave private LDS tiles, no atomics ----------------
__global__ __launch_bounds__(256) void kv_reduce(
    const u16* __restrict__ qkv, float* __restrict__ Pkv, float* __restrict__ PKsum)
{
    const int bh = blockIdx.x;            // 0..127
    const int b = bh >> 4, h = bh & 15;
    const int chunk = blockIdx.y;         // 0..7
    const int t = threadIdx.x;
    const int w = t >> 6, l = t & 63, lr = l & 15, quad = l >> 4;
    __shared__ u16 lds[4 * 2 * 2048];     // [wave][buf][K 1024 | V 1024] = 32 KB

    const int sbase = chunk * 512 + w * 128;
    const u16* qbase = qkv + (size_t)b * SEQ * 1536 + 512 + h * HD;  // K part; V = +512

    const int sl0 = l >> 2;               // rows 0..15 (instr 0)
    const int sl1 = 16 + sl0;             // rows 16..31 (instr 1)
    const int cl  = l & 3;
    const int cg0 = (cl + (sl0 >> 3)) & 3;
    const int cg1 = (cl + (sl1 >> 3)) & 3;
    const int gof0 = sl0 * 1536 + cg0 * 8;
    const int gof1 = sl1 * 1536 + cg1 * 8;

    u16* myl = lds + w * 4096;

    const int offA0 = quad * 256 + ((((lr >> 3) + 0) - quad) & 3) * 8 + (lr & 7);  // d 0..15
    const int offA1 = quad * 256 + ((((lr >> 3) + 2) - quad) & 3) * 8 + (lr & 7);  // d 16..31

    floatx4 a00 = {0,0,0,0}, a01 = {0,0,0,0}, a10 = {0,0,0,0}, a11 = {0,0,0,0};
    float ks0 = 0.f, ks1 = 0.f;

    {
        const u16* gK = qbase + (size_t)sbase * 1536;
        g2lds16(gK + gof0,       myl);
        g2lds16(gK + gof1,       myl + 512);
        g2lds16(gK + 512 + gof0, myl + 1024);
        g2lds16(gK + 512 + gof1, myl + 1536);
    }
    #pragma unroll
    for (int st = 0; st < 4; st++) {
        if (st < 3) {                      // prefetch next buf before the drain
            const u16* gK = qbase + (size_t)(sbase + (st + 1) * 32) * 1536;
            u16* nl = myl + ((st + 1) & 1) * 2048;
            g2lds16(gK + gof0,       nl);
            g2lds16(gK + gof1,       nl + 512);
            g2lds16(gK + 512 + gof0, nl + 1024);
            g2lds16(gK + 512 + gof1, nl + 1536);
        }
        __syncthreads();                   // vmcnt(0) drain, compiler-safe fence
        const u16* lK = myl + (st & 1) * 2048;
        const u16* lV = lK + 1024;
        union { bf16x8 v; u16 u[8]; } fa0, fa1, fb0, fb1;
        #pragma unroll
        for (int j = 0; j < 8; j++) {
            fa0.u[j] = lK[offA0 + j * 32];
            fa1.u[j] = lK[offA1 + j * 32];
            fb0.u[j] = lV[offA0 + j * 32];
            fb1.u[j] = lV[offA1 + j * 32];
        }
        #pragma unroll
        for (int j = 0; j < 8; j++) { ks0 += bf2f(fa0.u[j]); ks1 += bf2f(fa1.u[j]); }
        a00 = __builtin_amdgcn_mfma_f32_16x16x32_bf16(fa0.v, fb0.v, a00, 0, 0, 0);
        a01 = __builtin_amdgcn_mfma_f32_16x16x32_bf16(fa0.v, fb1.v, a01, 0, 0, 0);
        a10 = __builtin_amdgcn_mfma_f32_16x16x32_bf16(fa1.v, fb0.v, a10, 0, 0, 0);
        a11 = __builtin_amdgcn_mfma_f32_16x16x32_bf16(fa1.v, fb1.v, a11, 0, 0, 0);
    }

    const int p = bh * 32 + chunk * 4 + w;
    float* dst = Pkv + (size_t)p * 1024;
    floatx4 accs[2][2] = {{a00, a01}, {a10, a11}};
    #pragma unroll
    for (int i = 0; i < 2; i++)
        #pragma unroll
        for (int j = 0; j < 2; j++)
            #pragma unroll
            for (int r = 0; r < 4; r++)
                dst[(i * 16 + quad * 4 + r) * 32 + j * 16 + lr] = accs[i][j][r];

    float k0 = ks0 + __shfl_xor(ks0, 16); k0 += __shfl_xor(k0, 32);
    float k1 = ks1 + __shfl_xor(ks1, 16); k1 += __shfl_xor(k1, 32);
    if (quad == 0) {
        PKsum[p * 32 + lr]      = k0;
        PKsum[p * 32 + 16 + lr] = k1;
    }
}

// ---------------- final reduce: KV[bh][1024] = sum of 32 partials; Ksum likewise ----------------
__global__ __launch_bounds__(256) void kv_final(
    const float* __restrict__ Pkv, const float* __restrict__ PKsum,
    float* __restrict__ KV, float* __restrict__ Ksum)
{
    const int bh = blockIdx.x;
    const int t = threadIdx.x;
    float a0 = 0.f, a1 = 0.f, a2 = 0.f, a3 = 0.f;
    for (int p = 0; p < 32; p++) {
        const float* src = Pkv + ((size_t)bh * 32 + p) * 1024;
        a0 += src[t];
        a1 += src[t + 256];
        a2 += src[t + 512];
        a3 += src[t + 768];
    }
    float* dst = KV + (size_t)bh * 1024;
    dst[t] = a0; dst[t + 256] = a1; dst[t + 512] = a2; dst[t + 768] = a3;
    if (t < 32) {
        float s = 0.f;
        for (int p = 0; p < 32; p++) s += PKsum[(bh * 32 + p) * 32 + t];
        Ksum[bh * 32 + t] = s;
    }
}

// ---------------- msg = (Q . KV) * SEQ / (Q . Ksum + eps) ----------------
__global__ __launch_bounds__(256) void msg_kernel(
    const u16* __restrict__ qkv, const float* __restrict__ KV,
    const float* __restrict__ Ksum, u16* __restrict__ msg)
{
    int blk = blockIdx.x;           // 1024 blocks
    int b = blk >> 7;
    int r0 = (blk & 127) * 32;
    int t = threadIdx.x;
    int h = t >> 4;
    int vd = (t & 15) * 2;
    float kv0[32], kv1[32], ksr[32];
    const float* kvh = KV + ((size_t)b * 16 + h) * 1024;
    const float* ksh = Ksum + (b * 16 + h) * 32;
    #pragma unroll
    for (int d = 0; d < 32; d++) {
        kv0[d] = kvh[d * 32 + vd];
        kv1[d] = kvh[d * 32 + vd + 1];
        ksr[d] = ksh[d];
    }
    __shared__ u16 Qs[4 * 512];
    const int srr = t >> 6;
    const int scc = (t & 63) * 8;
    for (int rg = 0; rg < 32; rg += 4) {
        size_t row = (size_t)b * SEQ + r0 + rg;
        uint4 qv = *(const uint4*)(qkv + (row + srr) * 1536 + scc);
        __syncthreads();
        *(uint4*)(Qs + srr * 512 + scc) = qv;
        __syncthreads();
        #pragma unroll
        for (int r2 = 0; r2 < 4; r2++) {
            const u16* qp = Qs + r2 * 512 + h * HD;
            float q[32];
            #pragma unroll
            for (int i0 = 0; i0 < 32; i0 += 8) {
                union { uint4 v; u16 u[8]; } uu;
                uu.v = *(const uint4*)(qp + i0);
                #pragma unroll
                for (int jq = 0; jq < 8; jq++) q[i0 + jq] = bf2f(uu.u[jq]);
            }
            float zdot = 0.f, m0 = 0.f, m1 = 0.f;
            #pragma unroll
            for (int d = 0; d < 32; d++) {
                float qd = q[d];
                zdot += qd * ksr[d];
                m0   += qd * kv0[d];
                m1   += qd * kv1[d];
            }
            float z = (float)SEQ / (zdot + 1e-6f);
            unsigned pack = (unsigned)f2bf(m0 * z) | ((unsigned)f2bf(m1 * z) << 16);
            *(unsigned*)(msg + (row + r2) * C + h * HD + vd) = pack;
        }
    }
}

extern "C" void kernel_launch(void* const* d_in, const int* in_sizes, int n_in,
                              void* d_out, int out_size, void* d_ws, size_t ws_size,
                              hipStream_t stream) {
    const float* x     = (const float*)d_in[0];
    const float* Wq    = (const float*)d_in[1];
    const float* Wk    = (const float*)d_in[2];
    const float* Wv    = (const float*)d_in[3];
    const float* Wm    = (const float*)d_in[4];
    const float* W1    = (const float*)d_in[5];
    const float* b1    = (const float*)d_in[6];
    const float* W2    = (const float*)d_in[7];
    const float* b2    = (const float*)d_in[8];
    const float* g_att = (const float*)d_in[9];
    const float* b_att = (const float*)d_in[10];
    const float* g_ffn = (const float*)d_in[11];
    const float* b_ffn = (const float*)d_in[12];
    float* out = (float*)d_out;

    // Workspace map (live ranges disjoint in time) - see R5 notes
    char* ws = (char*)d_ws;
    u16*   Wqkvt = (u16*)(ws);                    // 1.5 MB
    u16*   Wmt   = (u16*)(ws + 0x180000);         // 0.5 MB
    u16*   W1t   = (u16*)(ws + 0x200000);         // 0.5 MB
    u16*   W2t   = (u16*)(ws + 0x280000);         // 0.5 MB
    float* KV    = (float*)(ws + 0x300000);       // 512 KB
    float* Ksum  = (float*)(ws + 0x380000);       // 16 KB
    u16*   hb    = (u16*)(ws + 0x400000);         // 32 MB (LN1 out; reused as msg)
    float* Pkv   = (float*)(ws + 0x400000);       // 16 MB, aliases hb (hb dead in step 4)
    float* PKsum = (float*)(ws + 0x1400000);      // 512 KB
    u16*   qkv   = (u16*)(ws + 0x2400000);        // 96 MB
    u16*   h2    = qkv;                           // 32 MB (qkv dead after step 5)
    u16*   f1    = (u16*)(ws + 0x4400000);        // 32 MB (in qkv tail, dead by step 8)

    // 1. weights -> bf16 transposed
    prep_weights<<<6 * 64, 256, 0, stream>>>(Wq, Wk, Wv, Wm, W1, W2,
                                             Wqkvt, Wmt, W1t, W2t);
    // 2. LN1
    ln_kernel<<<ROWS / 4, 256, 0, stream>>>(x, g_att, b_att, hb);
    // 3. qkv = h @ [Wq|Wk|Wv] with feature-map epilogue  (linear grid, XCD swizzle)
    gemm_tile<0><<<12 * 256, 256, 0, stream>>>(hb, Wqkvt, 512, 1536, 256,
                                               qkv, nullptr, nullptr, nullptr);
    // 4. KV/Ksum: MFMA partials + final reduce (no atomics, no memset)
    kv_reduce<<<dim3(128, 8), 256, 0, stream>>>(qkv, Pkv, PKsum);
    kv_final<<<128, 256, 0, stream>>>(Pkv, PKsum, KV, Ksum);
    // 5. msg (overwrites hb region - Pkv already consumed)
    msg_kernel<<<1024, 256, 0, stream>>>(qkv, KV, Ksum, hb);
    // 6. x2 = x + msg @ Wm   (x2 lives in d_out)
    gemm_tile<1><<<4 * 256, 256, 0, stream>>>(hb, Wmt, 512, 512, 256,
                                              nullptr, out, nullptr, x);
    // 7. LN2
    ln_kernel<<<ROWS / 4, 256, 0, stream>>>(out, g_ffn, b_ffn, h2);
    // 8. f1 = gelu(h2 @ W1 + b1)
    gemm_tile<2><<<4 * 256, 256, 0, stream>>>(h2, W1t, 512, 512, 256,
                                              f1, nullptr, b1, nullptr);
    // 9. out = x2 + f1 @ W2 + b2   (in place on d_out)
    gemm_tile<3><<<4 * 256, 256, 0, stream>>>(f1, W2t, 512, 512, 256,
                                              nullptr, out, b2, nullptr);
}